// Round 4
// baseline (1710.528 us; speedup 1.0000x reference)
//
#include <hip/hip_runtime.h>

#define QN 8
#define KN 1024
#define DN 256
#define NROWS 32768
#define IDX_BASE 8388608
#define LOSS_OFF 8650752
#define MARGIN 8e-3f
#define LCAP 3072u

// ws layout (float offsets)
#define WS_LOSS 0
#define WS_CNORM 8
#define WS_ANORM 8200
#define WS_RESID 40968       // float[8388608]
#define WS_RSPLIT 8429576    // bf16[8388608] -> 4194304 floats
#define WS_CSPLIT 12623880   // bf16[2097152] -> 1048576 floats

typedef __attribute__((ext_vector_type(8))) short short8v;
typedef __attribute__((ext_vector_type(4))) float f32x4;

static __device__ __forceinline__ unsigned short f2bf(float x) {
  unsigned int u = __float_as_uint(x);
  unsigned int r = (u + 0x7fffu + ((u >> 16) & 1u)) >> 16;
  return (unsigned short)r;
}

// numpy pairwise sum-of-squares over 256 floats (validated R1: absmax 0.0)
__device__ __forceinline__ float sum256_sq_np(const float* p) {
  float h[2];
#pragma unroll
  for (int half = 0; half < 2; ++half) {
    const float* a = p + half * 128;
    float r[8];
#pragma unroll
    for (int j = 0; j < 8; ++j) r[j] = __fmul_rn(a[j], a[j]);
    for (int i = 8; i < 128; i += 8) {
#pragma unroll
      for (int j = 0; j < 8; ++j) r[j] = __fadd_rn(r[j], __fmul_rn(a[i + j], a[i + j]));
    }
    h[half] = __fadd_rn(__fadd_rn(__fadd_rn(r[0], r[1]), __fadd_rn(r[2], r[3])),
                        __fadd_rn(__fadd_rn(r[4], r[5]), __fadd_rn(r[6], r[7])));
  }
  return __fadd_rn(h[0], h[1]);
}

__global__ void rvq_prep_norm(const float* __restrict__ cb, float* __restrict__ ws) {
  int g = blockIdx.x * blockDim.x + threadIdx.x;
  if (g < 8) ws[WS_LOSS + g] = 0.f;
  if (g < QN * KN) ws[WS_CNORM + g] = sum256_sq_np(cb + (size_t)g * DN);
}

__global__ void rvq_prep_cast(const float* __restrict__ cb, unsigned short* __restrict__ cs) {
  int gid = blockIdx.x * blockDim.x + threadIdx.x;
  const float4* c4 = (const float4*)cb;
  ushort4* s4 = (ushort4*)cs;
#pragma unroll
  for (int k = 0; k < 4; ++k) {
    int i = gid + k * 131072;
    float4 v = c4[i];
    s4[i] = make_ushort4(f2bf(v.x), f2bf(v.y), f2bf(v.z), f2bf(v.w));
  }
}

// q=0 init: Anorm(z) np-exact + RSPLIT=bf16(z)
__global__ void rvq_init_rows(const float* __restrict__ z, float* __restrict__ ws) {
  int t = blockIdx.x * blockDim.x + threadIdx.x;
  ws[WS_ANORM + t] = sum256_sq_np(z + (size_t)t * DN);
  const float4* z4 = (const float4*)z;
  ushort4* r4 = (ushort4*)(ws + WS_RSPLIT);
#pragma unroll 8
  for (int i = 0; i < 64; ++i) {
    int idx = i * 32768 + t;
    float4 v = z4[idx];
    r4[idx] = make_ushort4(f2bf(v.x), f2bf(v.y), f2bf(v.z), f2bf(v.w));
  }
}

// Fused per-q: bf16 screen GEMM over all 1024 codes (8 chunks of 128),
// LDS candidate list w/ running-min window, in-LDS exact recheck
// (R1-validated serial fmaf chain + u64 min-key tie-break), np-exact update.
__global__ __launch_bounds__(256, 1) void rvq_fused(const float* __restrict__ z,
                                                    const float* __restrict__ cb,
                                                    float* __restrict__ ws,
                                                    float* __restrict__ out, int q) {
  __shared__ __align__(16) unsigned short As[128 * 64];   // 16 KB
  __shared__ __align__(16) unsigned short Bs[128 * 64];   // 16 KB
  __shared__ float an_s[128], cn_s[128];
  __shared__ unsigned int rowmin[128];                    // f32 bits (d>0 always)
  __shared__ unsigned long long chc[128];
  __shared__ unsigned int lcnt;
  __shared__ __align__(16) uint2 lcand[LCAP];             // 24 KB, reused as lr[16][264]

  const int tid = threadIdx.x;
  const int row0 = blockIdx.x * 128;
  const int wv = tid >> 6, lane = tid & 63, quad = lane >> 4, l15 = lane & 15;
  const float* rsrc = (q == 0) ? z : (ws + WS_RESID);

  const uint4* Ag = (const uint4*)(ws + WS_RSPLIT);
  const uint4* Bg = (const uint4*)((const unsigned short*)(ws + WS_CSPLIT) + (size_t)q * KN * DN);

  if (tid < 128) {
    an_s[tid] = ws[WS_ANORM + row0 + tid];
    rowmin[tid] = 0x7f7fffffu;
    chc[tid] = ~0ull;
  }
  if (tid == 0) lcnt = 0u;

  const int rb = tid >> 3, cch = tid & 7;
  f32x4 acc[4][4];
  uint4 pa[4], pb[4];
  // prefetch it=0
#pragma unroll
  for (int p = 0; p < 4; ++p) {
    int r = p * 32 + rb;
    pa[p] = Ag[(size_t)(row0 + r) * 32 + cch];
    pb[p] = Bg[(size_t)r * 32 + cch];
  }

  for (int it = 0; it < 32; ++it) {
    const int c = it >> 2, kk = it & 3;
    __syncthreads();                       // prev slice consumers done (also covers init)
#pragma unroll
    for (int p = 0; p < 4; ++p) {
      int r = p * 32 + rb;
      int cp = cch ^ (r & 7);
      ((uint4*)As)[r * 8 + cp] = pa[p];
      ((uint4*)Bs)[r * 8 + cp] = pb[p];
    }
    if (kk == 0 && tid < 128) cn_s[tid] = ws[WS_CNORM + q * KN + c * 128 + tid];
    if (it + 1 < 32) {                     // prefetch next slice (latency hidden by MFMA)
      int c2 = (it + 1) >> 2, kk2 = (it + 1) & 3;
#pragma unroll
      for (int p = 0; p < 4; ++p) {
        int r = p * 32 + rb;
        pa[p] = Ag[(size_t)(row0 + r) * 32 + kk2 * 8 + cch];
        pb[p] = Bg[(size_t)(c2 * 128 + r) * 32 + kk2 * 8 + cch];
      }
    }
    __syncthreads();

    if (kk == 0) {
#pragma unroll
      for (int i = 0; i < 4; ++i)
#pragma unroll
        for (int j = 0; j < 4; ++j) acc[i][j] = (f32x4){0.f, 0.f, 0.f, 0.f};
    }
#pragma unroll
    for (int s = 0; s < 2; ++s) {
      short8v a[4], b[4];
      int ph = (s * 4 + quad) ^ (l15 & 7);
#pragma unroll
      for (int i = 0; i < 4; ++i) {
        int ra = (wv >> 1) * 64 + i * 16 + l15;
        int rc = (wv & 1) * 64 + i * 16 + l15;
        a[i] = *(const short8v*)&As[ra * 64 + ph * 8];
        b[i] = *(const short8v*)&Bs[rc * 64 + ph * 8];
      }
#pragma unroll
      for (int i = 0; i < 4; ++i)
#pragma unroll
        for (int j = 0; j < 4; ++j)
          acc[i][j] = __builtin_amdgcn_mfma_f32_16x16x32_bf16(a[i], b[j], acc[i][j], 0, 0, 0);
    }

    if (kk == 3) {                         // chunk epilogue: min-merge + append
#pragma unroll
      for (int i = 0; i < 4; ++i) {
#pragma unroll
        for (int reg = 0; reg < 4; ++reg) {
          int rl = (wv >> 1) * 64 + i * 16 + quad * 4 + reg;
          float an = an_s[rl];
          float bd = 3.402823466e+38f;
#pragma unroll
          for (int j = 0; j < 4; ++j) {
            int cl = (wv & 1) * 64 + j * 16 + l15;
            float d = __fadd_rn(__fadd_rn(an, -2.0f * acc[i][j][reg]), cn_s[cl]);
            bd = (d < bd) ? d : bd;
          }
#pragma unroll
          for (int m = 1; m <= 8; m <<= 1) {
            float od = __shfl_xor(bd, m, 64);
            bd = (od < bd) ? od : bd;
          }
          if (l15 == 0) atomicMin(&rowmin[rl], __float_as_uint(bd));
        }
      }
      __syncthreads();                     // running min (incl. this chunk) visible
#pragma unroll
      for (int i = 0; i < 4; ++i) {
#pragma unroll
        for (int reg = 0; reg < 4; ++reg) {
          int rl = (wv >> 1) * 64 + i * 16 + quad * 4 + reg;
          float an = an_s[rl];
          float thr = __uint_as_float(rowmin[rl]) + MARGIN;
#pragma unroll
          for (int j = 0; j < 4; ++j) {
            int cl = (wv & 1) * 64 + j * 16 + l15;
            float d = __fadd_rn(__fadd_rn(an, -2.0f * acc[i][j][reg]), cn_s[cl]);
            if (d <= thr) {
              unsigned int p = atomicAdd(&lcnt, 1u);
              if (p < LCAP)
                lcand[p] = make_uint2(__float_as_uint(d),
                                      ((unsigned)rl << 10) | (unsigned)(c * 128 + cl));
            }
          }
        }
      }
    }
  }
  __syncthreads();

  // ---- exact recheck (in-LDS) ----
  const float* cbq = cb + (size_t)q * KN * DN;
  const float* cnq = ws + WS_CNORM + q * KN;
  unsigned int n = lcnt;
  if (n <= LCAP) {
    for (unsigned int e = tid; e < n; e += 256u) {
      uint2 en = lcand[e];
      int rl = en.y >> 10, code = en.y & 1023;
      float thr = __uint_as_float(rowmin[rl]) + MARGIN;
      if (__uint_as_float(en.x) > thr) continue;
      const float* r = rsrc + (size_t)(row0 + rl) * DN;
      const float* cc = cbq + (size_t)code * DN;
      float B = 0.f;
#pragma unroll 16
      for (int d = 0; d < DN; ++d) B = fmaf(r[d], cc[d], B);   // R1-exact serial chain
      float de = __fadd_rn(__fadd_rn(an_s[rl], -2.0f * B), cnq[code]);
      unsigned long long key = ((unsigned long long)__float_as_uint(de) << 32) | (unsigned)code;
      atomicMin(&chc[rl], key);
    }
  } else {
    // overflow fallback: exhaustive exact argmin (correct, slow, expected never)
    for (int e = tid; e < 128 * 1024; e += 256) {
      int rl = e >> 10, code = e & 1023;
      const float* r = rsrc + (size_t)(row0 + rl) * DN;
      const float* cc = cbq + (size_t)code * DN;
      float B = 0.f;
#pragma unroll 16
      for (int d = 0; d < DN; ++d) B = fmaf(r[d], cc[d], B);
      float de = __fadd_rn(__fadd_rn(an_s[rl], -2.0f * B), cnq[code]);
      unsigned long long key = ((unsigned long long)__float_as_uint(de) << 32) | (unsigned)code;
      atomicMin(&chc[rl], key);
    }
  }
  __syncthreads();

  // ---- np-exact update: 8 passes x 16 rows, 16 thr/row x 16 dims ----
  float (*lr)[264] = (float(*)[264])lcand;   // lcand dead; 16*264*4=16.9KB <= 24KB
  const bool last = (q == QN - 1);
  const int ur = tid >> 4, ud = tid & 15;
  float lp = 0.f;
  for (int pass = 0; pass < 8; ++pass) {
    int rl = pass * 16 + ur;
    int row = row0 + rl;
    int idx = (int)(chc[rl] & 1023u);
    if (ud == 0) out[IDX_BASE + (size_t)q * NROWS + row] = (float)idx;

    const float4* r4 = (const float4*)(rsrc + (size_t)row * DN) + ud * 4;
    const float4* q4 = (const float4*)(cb + ((size_t)q * KN + idx) * DN) + ud * 4;
    float4 rnb[4];
#pragma unroll
    for (int t = 0; t < 4; ++t) {
      float4 r = r4[t], qv = q4[t];
      float tx = __fadd_rn(qv.x, -r.x), ty = __fadd_rn(qv.y, -r.y);
      float tz = __fadd_rn(qv.z, -r.z), tw = __fadd_rn(qv.w, -r.w);
      float sx = __fadd_rn(r.x, tx), sy = __fadd_rn(r.y, ty);
      float sz = __fadd_rn(r.z, tz), sw = __fadd_rn(r.w, tw);
      rnb[t] = make_float4(__fadd_rn(r.x, -sx), __fadd_rn(r.y, -sy),
                           __fadd_rn(r.z, -sz), __fadd_rn(r.w, -sw));
      lp = fmaf(tx, tx, lp); lp = fmaf(ty, ty, lp);
      lp = fmaf(tz, tz, lp); lp = fmaf(tw, tw, lp);
    }

    if (last) {
      const float4* z4 = (const float4*)(z + (size_t)row * DN) + ud * 4;
      float4* o4 = (float4*)(out + (size_t)row * DN) + ud * 4;
#pragma unroll
      for (int t = 0; t < 4; ++t) {
        float4 zv = z4[t];
        o4[t] = make_float4(__fadd_rn(zv.x, -rnb[t].x), __fadd_rn(zv.y, -rnb[t].y),
                            __fadd_rn(zv.z, -rnb[t].z), __fadd_rn(zv.w, -rnb[t].w));
      }
    } else {
      float4* rd = (float4*)(ws + WS_RESID + (size_t)row * DN) + ud * 4;
      ushort4* rs = (ushort4*)((unsigned short*)(ws + WS_RSPLIT) + (size_t)row * DN) + ud * 4;
#pragma unroll
      for (int t = 0; t < 4; ++t) {
        float4 v = rnb[t];
        rd[t] = v;
        rs[t] = make_ushort4(f2bf(v.x), f2bf(v.y), f2bf(v.z), f2bf(v.w));
        *(float4*)&lr[ur][ud * 16 + t * 4] = v;
      }
      __syncthreads();
      if (tid < 16) ws[WS_ANORM + row0 + pass * 16 + tid] = sum256_sq_np(&lr[tid][0]);
      __syncthreads();
    }
  }

#pragma unroll
  for (int off = 32; off > 0; off >>= 1) lp += __shfl_down(lp, off, 64);
  if (lane == 0) atomicAdd(ws + WS_LOSS + q, lp);
}

__global__ void rvq_fin(const float* __restrict__ ws, float* __restrict__ out) {
  if (blockIdx.x == 0 && threadIdx.x == 0) {
    float vq = 0.f;
    for (int q = 0; q < QN; ++q) {
      float m = ws[WS_LOSS + q] / 8388608.0f;
      float l = __fadd_rn(m, 0.25f * m);
      vq = __fadd_rn(vq, l);
    }
    out[LOSS_OFF] = vq;
  }
}

extern "C" void kernel_launch(void* const* d_in, const int* in_sizes, int n_in,
                              void* d_out, int out_size, void* d_ws, size_t ws_size,
                              hipStream_t stream) {
  const float* z = (const float*)d_in[0];
  const float* cb = (const float*)d_in[1];
  float* out = (float*)d_out;
  float* ws = (float*)d_ws;

  hipLaunchKernelGGL(rvq_prep_norm, dim3(32), dim3(256), 0, stream, cb, ws);
  hipLaunchKernelGGL(rvq_prep_cast, dim3(512), dim3(256), 0, stream, cb,
                     (unsigned short*)(ws + WS_CSPLIT));
  hipLaunchKernelGGL(rvq_init_rows, dim3(128), dim3(256), 0, stream, z, ws);

  for (int q = 0; q < QN; ++q)
    hipLaunchKernelGGL(rvq_fused, dim3(256), dim3(256), 0, stream, z, cb, ws, out, q);

  hipLaunchKernelGGL(rvq_fin, dim3(1), dim3(64), 0, stream, ws, out);
}

// Round 5
// 1497.623 us; speedup vs baseline: 1.1422x; 1.1422x over previous
//
#include <hip/hip_runtime.h>

#define QN 8
#define KN 1024
#define DN 256
#define NROWS 32768
#define IDX_BASE 8388608
#define LOSS_OFF 8650752
#define MARGIN 5e-3f
#define LCAP 8192u

// ws layout (float offsets)
#define WS_LOSS 0
#define WS_CNORM 8
#define WS_ANORM 8200
#define WS_RESID 40968       // float[8388608]
#define WS_RSPLIT 8429576    // bf16[8388608] -> 4194304 floats
#define WS_CSPLIT 12623880   // bf16[2097152] -> 1048576 floats

// dynamic LDS layout (bytes)
#define SM_AFULL 0           // 65536: A row-tile 128x256 bf16, 4 swizzled kk-slices
#define SM_BS    65536       // 16384: B slice 128x64 bf16, swizzled
#define SM_LCAND 81920       // 65536: uint2[8192]; aliased as lr[16][260] in update
#define SM_CHC   147456      // 1024
#define SM_ANS   148480      // 512
#define SM_CNS   148992      // 512
#define SM_RMIN  149504      // 512
#define SM_LCNT  150016      // 16
#define SM_BYTES 150032

typedef __attribute__((ext_vector_type(8))) short short8v;
typedef __attribute__((ext_vector_type(4))) float f32x4;

static __device__ __forceinline__ unsigned short f2bf(float x) {
  unsigned int u = __float_as_uint(x);
  unsigned int r = (u + 0x7fffu + ((u >> 16) & 1u)) >> 16;
  return (unsigned short)r;
}

// numpy pairwise sum-of-squares over 256 floats (validated R1: absmax 0.0)
__device__ __forceinline__ float sum256_sq_np(const float* p) {
  float h[2];
#pragma unroll
  for (int half = 0; half < 2; ++half) {
    const float* a = p + half * 128;
    float r[8];
#pragma unroll
    for (int j = 0; j < 8; ++j) r[j] = __fmul_rn(a[j], a[j]);
    for (int i = 8; i < 128; i += 8) {
#pragma unroll
      for (int j = 0; j < 8; ++j) r[j] = __fadd_rn(r[j], __fmul_rn(a[i + j], a[i + j]));
    }
    h[half] = __fadd_rn(__fadd_rn(__fadd_rn(r[0], r[1]), __fadd_rn(r[2], r[3])),
                        __fadd_rn(__fadd_rn(r[4], r[5]), __fadd_rn(r[6], r[7])));
  }
  return __fadd_rn(h[0], h[1]);
}

__global__ void rvq_prep_norm(const float* __restrict__ cb, float* __restrict__ ws) {
  int g = blockIdx.x * blockDim.x + threadIdx.x;
  if (g < 8) ws[WS_LOSS + g] = 0.f;
  if (g < QN * KN) ws[WS_CNORM + g] = sum256_sq_np(cb + (size_t)g * DN);
}

__global__ void rvq_prep_cast(const float* __restrict__ cb, unsigned short* __restrict__ cs) {
  int gid = blockIdx.x * blockDim.x + threadIdx.x;
  const float4* c4 = (const float4*)cb;
  ushort4* s4 = (ushort4*)cs;
#pragma unroll
  for (int k = 0; k < 4; ++k) {
    int i = gid + k * 131072;
    float4 v = c4[i];
    s4[i] = make_ushort4(f2bf(v.x), f2bf(v.y), f2bf(v.z), f2bf(v.w));
  }
}

// q=0 init: Anorm(z) np-exact + RSPLIT=bf16(z)
__global__ void rvq_init_rows(const float* __restrict__ z, float* __restrict__ ws) {
  int t = blockIdx.x * blockDim.x + threadIdx.x;
  ws[WS_ANORM + t] = sum256_sq_np(z + (size_t)t * DN);
  const float4* z4 = (const float4*)z;
  ushort4* r4 = (ushort4*)(ws + WS_RSPLIT);
#pragma unroll 8
  for (int i = 0; i < 64; ++i) {
    int idx = i * 32768 + t;
    float4 v = z4[idx];
    r4[idx] = make_ushort4(f2bf(v.x), f2bf(v.y), f2bf(v.z), f2bf(v.w));
  }
}

// Fused per-q: A row-tile resident in LDS all q; B slices streamed.
// bf16 screen GEMM (8 chunks of 128 codes), LDS candidate list w/ running-min
// window, in-LDS exact recheck (R1-validated serial fmaf + u64 min-key
// tie-break), np-exact update.
__global__ __launch_bounds__(256, 1) void rvq_fused(const float* __restrict__ z,
                                                    const float* __restrict__ cb,
                                                    float* __restrict__ ws,
                                                    float* __restrict__ out, int q) {
  extern __shared__ __align__(16) char smem[];
  uint4* Afull = (uint4*)(smem + SM_AFULL);            // 4096 uint4
  uint4* Bs4 = (uint4*)(smem + SM_BS);                 // 1024 uint4
  uint2* lcand = (uint2*)(smem + SM_LCAND);
  unsigned long long* chc = (unsigned long long*)(smem + SM_CHC);
  float* an_s = (float*)(smem + SM_ANS);
  float* cn_s = (float*)(smem + SM_CNS);
  unsigned int* rowmin = (unsigned int*)(smem + SM_RMIN);
  unsigned int* lcnt = (unsigned int*)(smem + SM_LCNT);
  const unsigned short* Ash = (const unsigned short*)Afull;
  const unsigned short* Bsh = (const unsigned short*)Bs4;

  const int tid = threadIdx.x;
  const int row0 = blockIdx.x * 128;
  const int wv = tid >> 6, lane = tid & 63, quad = lane >> 4, l15 = lane & 15;
  const float* rsrc = (q == 0) ? z : (ws + WS_RESID);

  const uint4* Ag = (const uint4*)(ws + WS_RSPLIT);
  const uint4* Bg = (const uint4*)((const unsigned short*)(ws + WS_CSPLIT) + (size_t)q * KN * DN);

  if (tid < 128) {
    an_s[tid] = ws[WS_ANORM + row0 + tid];
    rowmin[tid] = 0x7f7fffffu;
    chc[tid] = ~0ull;
  }
  if (tid == 0) *lcnt = 0u;

  const int rb = tid >> 3, cch = tid & 7;
  // Stage the full A row-tile once (swizzled per kk-slice)
#pragma unroll
  for (int kk2 = 0; kk2 < 4; ++kk2) {
#pragma unroll
    for (int p = 0; p < 4; ++p) {
      int r = p * 32 + rb;
      Afull[kk2 * 1024 + r * 8 + (cch ^ (r & 7))] = Ag[(size_t)(row0 + r) * 32 + kk2 * 8 + cch];
    }
  }

  f32x4 acc[4][4];
  uint4 pb[4];
#pragma unroll
  for (int p = 0; p < 4; ++p) pb[p] = Bg[(size_t)(p * 32 + rb) * 32 + cch];

  for (int it = 0; it < 32; ++it) {
    const int c = it >> 2, kk = it & 3;
    __syncthreads();                       // prev slice consumers done (covers init/A-stage)
#pragma unroll
    for (int p = 0; p < 4; ++p) {
      int r = p * 32 + rb;
      Bs4[r * 8 + (cch ^ (r & 7))] = pb[p];
    }
    if (kk == 0 && tid < 128) cn_s[tid] = ws[WS_CNORM + q * KN + c * 128 + tid];
    if (it + 1 < 32) {                     // prefetch next B slice
      int c2 = (it + 1) >> 2, kk2 = (it + 1) & 3;
#pragma unroll
      for (int p = 0; p < 4; ++p)
        pb[p] = Bg[(size_t)(c2 * 128 + p * 32 + rb) * 32 + kk2 * 8 + cch];
    }
    __syncthreads();

    if (kk == 0) {
#pragma unroll
      for (int i = 0; i < 4; ++i)
#pragma unroll
        for (int j = 0; j < 4; ++j) acc[i][j] = (f32x4){0.f, 0.f, 0.f, 0.f};
    }
#pragma unroll
    for (int s = 0; s < 2; ++s) {
      short8v a[4], b[4];
      int ph = (s * 4 + quad) ^ (l15 & 7);
#pragma unroll
      for (int i = 0; i < 4; ++i) {
        int ra = (wv >> 1) * 64 + i * 16 + l15;
        int rc = (wv & 1) * 64 + i * 16 + l15;
        a[i] = *(const short8v*)&Ash[kk * 8192 + ra * 64 + ph * 8];
        b[i] = *(const short8v*)&Bsh[rc * 64 + ph * 8];
      }
#pragma unroll
      for (int i = 0; i < 4; ++i)
#pragma unroll
        for (int j = 0; j < 4; ++j)
          acc[i][j] = __builtin_amdgcn_mfma_f32_16x16x32_bf16(a[i], b[j], acc[i][j], 0, 0, 0);
    }

    if (kk == 3) {                         // chunk epilogue: min-merge + append
#pragma unroll
      for (int i = 0; i < 4; ++i) {
#pragma unroll
        for (int reg = 0; reg < 4; ++reg) {
          int rl = (wv >> 1) * 64 + i * 16 + quad * 4 + reg;
          float an = an_s[rl];
          float bd = 3.402823466e+38f;
#pragma unroll
          for (int j = 0; j < 4; ++j) {
            int cl = (wv & 1) * 64 + j * 16 + l15;
            float d = __fadd_rn(__fadd_rn(an, -2.0f * acc[i][j][reg]), cn_s[cl]);
            bd = (d < bd) ? d : bd;
          }
#pragma unroll
          for (int m = 1; m <= 8; m <<= 1) {
            float od = __shfl_xor(bd, m, 64);
            bd = (od < bd) ? od : bd;
          }
          if (l15 == 0) atomicMin(&rowmin[rl], __float_as_uint(bd));
        }
      }
      __syncthreads();                     // running min (incl. this chunk) visible
#pragma unroll
      for (int i = 0; i < 4; ++i) {
#pragma unroll
        for (int reg = 0; reg < 4; ++reg) {
          int rl = (wv >> 1) * 64 + i * 16 + quad * 4 + reg;
          float an = an_s[rl];
          float thr = __uint_as_float(rowmin[rl]) + MARGIN;
#pragma unroll
          for (int j = 0; j < 4; ++j) {
            int cl = (wv & 1) * 64 + j * 16 + l15;
            float d = __fadd_rn(__fadd_rn(an, -2.0f * acc[i][j][reg]), cn_s[cl]);
            if (d <= thr) {
              unsigned int p = atomicAdd(lcnt, 1u);
              if (p < LCAP)
                lcand[p] = make_uint2(__float_as_uint(d),
                                      ((unsigned)rl << 10) | (unsigned)(c * 128 + cl));
            }
          }
        }
      }
    }
  }
  __syncthreads();

  // ---- exact recheck (in-LDS) ----
  const float* cbq = cb + (size_t)q * KN * DN;
  const float* cnq = ws + WS_CNORM + q * KN;
  unsigned int n = *lcnt;
  if (n <= LCAP) {
    for (unsigned int e = tid; e < n; e += 256u) {
      uint2 en = lcand[e];
      int rl = en.y >> 10, code = en.y & 1023;
      float thr = __uint_as_float(rowmin[rl]) + MARGIN;
      if (__uint_as_float(en.x) > thr) continue;
      const float* r = rsrc + (size_t)(row0 + rl) * DN;
      const float* cc = cbq + (size_t)code * DN;
      float B = 0.f;
#pragma unroll 16
      for (int d = 0; d < DN; ++d) B = fmaf(r[d], cc[d], B);   // R1-exact serial chain
      float de = __fadd_rn(__fadd_rn(an_s[rl], -2.0f * B), cnq[code]);
      unsigned long long key = ((unsigned long long)__float_as_uint(de) << 32) | (unsigned)code;
      atomicMin(&chc[rl], key);
    }
  } else {
    // safety fallback: exhaustive exact argmin (correct; expected never at LCAP=8192)
    for (int e = tid; e < 128 * 1024; e += 256) {
      int rl = e >> 10, code = e & 1023;
      const float* r = rsrc + (size_t)(row0 + rl) * DN;
      const float* cc = cbq + (size_t)code * DN;
      float B = 0.f;
#pragma unroll 16
      for (int d = 0; d < DN; ++d) B = fmaf(r[d], cc[d], B);
      float de = __fadd_rn(__fadd_rn(an_s[rl], -2.0f * B), cnq[code]);
      unsigned long long key = ((unsigned long long)__float_as_uint(de) << 32) | (unsigned)code;
      atomicMin(&chc[rl], key);
    }
  }
  __syncthreads();

  // ---- np-exact update: 8 passes x 16 rows, 16 thr/row x 16 dims ----
  float (*lr)[260] = (float(*)[260])(smem + SM_LCAND);   // lcand dead; stride 260: b128 at 8-lane/bank floor
  const bool last = (q == QN - 1);
  const int ur = tid >> 4, ud = tid & 15;
  float lp = 0.f;
  for (int pass = 0; pass < 8; ++pass) {
    int rl = pass * 16 + ur;
    int row = row0 + rl;
    int idx = (int)(chc[rl] & 1023u);
    if (ud == 0) out[IDX_BASE + (size_t)q * NROWS + row] = (float)idx;

    const float4* r4 = (const float4*)(rsrc + (size_t)row * DN) + ud * 4;
    const float4* q4 = (const float4*)(cb + ((size_t)q * KN + idx) * DN) + ud * 4;
    float4 rnb[4];
#pragma unroll
    for (int t = 0; t < 4; ++t) {
      float4 r = r4[t], qv = q4[t];
      float tx = __fadd_rn(qv.x, -r.x), ty = __fadd_rn(qv.y, -r.y);
      float tz = __fadd_rn(qv.z, -r.z), tw = __fadd_rn(qv.w, -r.w);
      float sx = __fadd_rn(r.x, tx), sy = __fadd_rn(r.y, ty);
      float sz = __fadd_rn(r.z, tz), sw = __fadd_rn(r.w, tw);
      rnb[t] = make_float4(__fadd_rn(r.x, -sx), __fadd_rn(r.y, -sy),
                           __fadd_rn(r.z, -sz), __fadd_rn(r.w, -sw));
      lp = fmaf(tx, tx, lp); lp = fmaf(ty, ty, lp);
      lp = fmaf(tz, tz, lp); lp = fmaf(tw, tw, lp);
    }

    if (last) {
      const float4* z4 = (const float4*)(z + (size_t)row * DN) + ud * 4;
      float4* o4 = (float4*)(out + (size_t)row * DN) + ud * 4;
#pragma unroll
      for (int t = 0; t < 4; ++t) {
        float4 zv = z4[t];
        o4[t] = make_float4(__fadd_rn(zv.x, -rnb[t].x), __fadd_rn(zv.y, -rnb[t].y),
                            __fadd_rn(zv.z, -rnb[t].z), __fadd_rn(zv.w, -rnb[t].w));
      }
    } else {
      float4* rd = (float4*)(ws + WS_RESID + (size_t)row * DN) + ud * 4;
      ushort4* rs = (ushort4*)((unsigned short*)(ws + WS_RSPLIT) + (size_t)row * DN) + ud * 4;
#pragma unroll
      for (int t = 0; t < 4; ++t) {
        float4 v = rnb[t];
        rd[t] = v;
        rs[t] = make_ushort4(f2bf(v.x), f2bf(v.y), f2bf(v.z), f2bf(v.w));
        *(float4*)&lr[ur][ud * 16 + t * 4] = v;
      }
      __syncthreads();
      if (tid < 16) ws[WS_ANORM + row0 + pass * 16 + tid] = sum256_sq_np(&lr[tid][0]);
      __syncthreads();
    }
  }

#pragma unroll
  for (int off = 32; off > 0; off >>= 1) lp += __shfl_down(lp, off, 64);
  if (lane == 0) atomicAdd(ws + WS_LOSS + q, lp);
}

__global__ void rvq_fin(const float* __restrict__ ws, float* __restrict__ out) {
  if (blockIdx.x == 0 && threadIdx.x == 0) {
    float vq = 0.f;
    for (int q = 0; q < QN; ++q) {
      float m = ws[WS_LOSS + q] / 8388608.0f;
      float l = __fadd_rn(m, 0.25f * m);
      vq = __fadd_rn(vq, l);
    }
    out[LOSS_OFF] = vq;
  }
}

extern "C" void kernel_launch(void* const* d_in, const int* in_sizes, int n_in,
                              void* d_out, int out_size, void* d_ws, size_t ws_size,
                              hipStream_t stream) {
  const float* z = (const float*)d_in[0];
  const float* cb = (const float*)d_in[1];
  float* out = (float*)d_out;
  float* ws = (float*)d_ws;

  hipLaunchKernelGGL(rvq_prep_norm, dim3(32), dim3(256), 0, stream, cb, ws);
  hipLaunchKernelGGL(rvq_prep_cast, dim3(512), dim3(256), 0, stream, cb,
                     (unsigned short*)(ws + WS_CSPLIT));
  hipLaunchKernelGGL(rvq_init_rows, dim3(128), dim3(256), 0, stream, z, ws);

  for (int q = 0; q < QN; ++q)
    hipLaunchKernelGGL(rvq_fused, dim3(256), dim3(256), SM_BYTES, stream, z, cb, ws, out, q);

  hipLaunchKernelGGL(rvq_fin, dim3(1), dim3(64), 0, stream, ws, out);
}